// Round 9
// baseline (155.476 us; speedup 1.0000x reference)
//
#include <hip/hip_runtime.h>

#define BB 32
#define CC 128
#define HH 128
#define WW 128
#define HWSZ (HH * WW)          // 16384
#define CHW (CC * HWSZ)         // 2097152
#define S4 (HWSZ / 4)           // 4096
#define RPB 8                   // output rows per block (kernel A)
#define HALO 14                 // RPB + 6

typedef float vfloat4 __attribute__((ext_vector_type(4)));

__device__ __forceinline__ vfloat4 fmax4(vfloat4 a, vfloat4 b) {
    vfloat4 r;
    r.x = fmaxf(a.x, b.x);
    r.y = fmaxf(a.y, b.y);
    r.z = fmaxf(a.z, b.z);
    r.w = fmaxf(a.w, b.w);
    return r;
}

// ---------- Kernel A: channel reduce + 7x7 conv + sigmoid -> sig [B][HW] ----
// One block = (batch, 8-row band). 512 blocks. Plain loads (seed L2/L3 for B).
__global__ __launch_bounds__(256, 2) void kA_reduce_conv(
    const float* __restrict__ x, const float* __restrict__ cw,
    float* __restrict__ sig) {
    __shared__ float m_lds[2][HALO][WW];   // 14 KiB
    __shared__ float wsh[2 * 49];

    const int tid = threadIdx.x;
    // XCD swizzle: adjacent h-bands of the same batch land on the same XCD.
    const int wg  = blockIdx.x;            // 0..511
    const int xcd = wg & 7;
    const int lin = wg >> 3;               // 0..63
    const int b   = xcd * 4 + (lin >> 4);  // 0..31
    const int hb  = lin & 15;              // 0..15
    const int h0  = hb * RPB;

    if (tid < 98) wsh[tid] = cw[tid];

    const int r0 = tid >> 5;               // 0..7
    const int w4 = tid & 31;               // float4 column 0..31
    const float* xb = x + (size_t)b * CHW;

    // ---------- Phase 1: channel reduce rows h0-3 .. h0+10 ----------
    const bool actB = (r0 < HALO - 8);     // r0 < 6 -> wave-uniform
    const int gh_a = h0 - 3 + r0;
    const int gh_b = h0 - 3 + r0 + 8;
    const bool okA = (gh_a >= 0) && (gh_a < HH);
    const bool okB = actB && (gh_b < HH);
    const int cha = gh_a < 0 ? 0 : (gh_a > HH - 1 ? HH - 1 : gh_a);
    const int chb = gh_b > HH - 1 ? HH - 1 : gh_b;

    const vfloat4* pA = (const vfloat4*)(xb + cha * WW) + w4;
    const vfloat4* pB = (const vfloat4*)(xb + chb * WW) + w4;

    vfloat4 sumA, mxA;
    {
        vfloat4 v = pA[0];
        sumA = v; mxA = v;
    }
    #pragma unroll 8
    for (int c = 1; c < CC; ++c) {
        vfloat4 v = pA[(size_t)c * S4];
        sumA += v;
        mxA = fmax4(mxA, v);
    }
    vfloat4 sumB = {0.f, 0.f, 0.f, 0.f}, mxB = sumB;
    if (actB) {                             // whole wave 3 skips
        vfloat4 v = pB[0];
        sumB = v; mxB = v;
        #pragma unroll 8
        for (int c = 1; c < CC; ++c) {
            vfloat4 t = pB[(size_t)c * S4];
            sumB += t;
            mxB = fmax4(mxB, t);
        }
    }

    const float invC = 1.0f / (float)CC;
    {
        vfloat4 avgA = sumA * invC;
        if (!okA) { avgA = (vfloat4){0,0,0,0}; mxA = (vfloat4){0,0,0,0}; }
        *(vfloat4*)&m_lds[0][r0][w4 * 4] = avgA;
        *(vfloat4*)&m_lds[1][r0][w4 * 4] = mxA;
        if (actB) {
            vfloat4 avgB = sumB * invC;
            if (!okB) { avgB = (vfloat4){0,0,0,0}; mxB = (vfloat4){0,0,0,0}; }
            *(vfloat4*)&m_lds[0][r0 + 8][w4 * 4] = avgB;
            *(vfloat4*)&m_lds[1][r0 + 8][w4 * 4] = mxB;
        }
    }
    __syncthreads();

    // ---------- Phase 2: conv 7x7 + sigmoid, conflict-free (R8 layout) ----
    {
        const int q = tid >> 7;            // 0..1 -> rows q*4 .. q*4+3
        const int w = tid & 127;
        float attn[4] = {0.f, 0.f, 0.f, 0.f};
        #pragma unroll
        for (int ic = 0; ic < 2; ++ic) {
            #pragma unroll
            for (int L = 0; L < 10; ++L) { // LDS row = q*4 + L
                const float* row = &m_lds[ic][q * 4 + L][0];
                #pragma unroll
                for (int kw = 0; kw < 7; ++kw) {
                    int wi = w - 3 + kw;
                    float v = (wi >= 0 && wi < WW) ? row[wi] : 0.0f;
                    #pragma unroll
                    for (int j = 0; j < 4; ++j) {
                        const int kh = L - j;          // compile-time after unroll
                        if (kh >= 0 && kh <= 6)
                            attn[j] = fmaf(v, wsh[ic * 49 + kh * 7 + kw], attn[j]);
                    }
                }
            }
        }
        #pragma unroll
        for (int j = 0; j < 4; ++j) {
            float sv = 1.0f / (1.0f + __expf(-attn[j]));
            sig[(size_t)b * HWSZ + (h0 + q * 4 + j) * WW + w] = sv;
        }
    }
}

// ---------- Kernel B: out = x * sig, reversed grid-stride stream ----------
// nt load on x (single-use, preserve L3 residency), nt store on out (R7 win),
// plain load on sig (heavy reuse across channels).
__global__ __launch_bounds__(256) void kB_mul(
    const float* __restrict__ x, const float* __restrict__ sig,
    float* __restrict__ out) {
    const int TOT4 = BB * CC * HWSZ / 4;          // 16777216
    int stride = gridDim.x * blockDim.x;
    for (int j = blockIdx.x * blockDim.x + threadIdx.x; j < TOT4; j += stride) {
        int i = TOT4 - 1 - j;                     // reversed: harvest A's L3 lines
        int b = i >> 19;                          // / (CHW/4)
        int s4 = i & (S4 - 1);
        vfloat4 xv = __builtin_nontemporal_load(reinterpret_cast<const vfloat4*>(x) + (size_t)i);
        vfloat4 sv = reinterpret_cast<const vfloat4*>(sig)[(size_t)b * S4 + s4];
        __builtin_nontemporal_store(xv * sv, reinterpret_cast<vfloat4*>(out) + (size_t)i);
    }
}

extern "C" void kernel_launch(void* const* d_in, const int* in_sizes, int n_in,
                              void* d_out, int out_size, void* d_ws, size_t ws_size,
                              hipStream_t stream) {
    const float* x  = (const float*)d_in[0];
    const float* cw = (const float*)d_in[1];
    float* out = (float*)d_out;
    float* sig = (float*)d_ws;    // [B][HW] = 2 MiB

    kA_reduce_conv<<<BB * (HH / RPB), 256, 0, stream>>>(x, cw, sig);  // 512 blocks
    kB_mul<<<8192, 256, 0, stream>>>(x, sig, out);
}